// Round 1
// 275.976 us; speedup vs baseline: 1.0153x; 1.0153x over previous
//
#include <hip/hip_runtime.h>

#define DD      64
#define ROWS    129        // 2D+1
#define NCOLS   262145     // N+1 (row stride, odd -> rows not mutually 16B aligned)
#define NDOT    262144     // N columns participate in the dot (last col excluded)
#define DOTROWS 128        // rows 0..127 need dots (Q's last row/col are zero)
#define CHUNK   2048       // columns per block in k_dot_copy
#define NCHUNK  128        // NDOT / CHUNK

// K1: grid = DOTROWS * NCHUNK blocks, 256 threads.
// Block (row, chunk): partial dot of Z[row, chunk-cols] with Z[128, chunk-cols],
// FUSED with the copy out[row, chunk-cols] = Z[row, chunk-cols].
// - Row-128 chunk staged to LDS via aligned float4 (128*NCOLS % 4 == 0).
// - Copy stores are NONTEMPORAL: out is never re-read, and we want Z (135 MB)
//   to stay resident in the 256 MiB L3 for k_row128's re-read.
__global__ __launch_bounds__(256) void k_dot_copy(const float* __restrict__ Z,
                                                  float* __restrict__ out,
                                                  float* __restrict__ partials) {
    const int row   = blockIdx.x & (DOTROWS - 1);
    const int chunk = blockIdx.x >> 7;
    const long base = (long)chunk * CHUNK;
    const float* zr = Z + (long)row * NCOLS + base;
    const float* zl = Z + (long)DOTROWS * NCOLS + base;   // row 128
    float* orow     = out + (long)row * NCOLS + base;
    const int tid = threadIdx.x;

    // stage the row-128 chunk (8 KB) into LDS with aligned float4 loads
    __shared__ float szl[CHUNK];
    const float4* zl4 = (const float4*)zl;   // 16B-aligned: (128*NCOLS + chunk*2048) % 4 == 0
#pragma unroll
    for (int k = 0; k < CHUNK / 4 / 256; ++k) {
        ((float4*)szl)[tid + k * 256] = zl4[tid + k * 256];
    }
    __syncthreads();

    float acc = 0.f;
#pragma unroll
    for (int k = 0; k < CHUNK / 256; ++k) {
        const int c = tid + k * 256;
        const float v = zr[c];
        __builtin_nontemporal_store(v, &orow[c]);   // fused copy, bypass/evict-early
        acc = fmaf(v, szl[c], acc);
    }
    // tail column (col NDOT) copy, once per row: not part of the dot (M zeroes it)
    if (chunk == NCHUNK - 1 && tid == 255) {
        __builtin_nontemporal_store(Z[(long)row * NCOLS + NDOT],
                                    &out[(long)row * NCOLS + NDOT]);
    }

    // wave (64-lane) reduce, then cross-wave via LDS
#pragma unroll
    for (int off = 32; off; off >>= 1) acc += __shfl_down(acc, off, 64);
    __shared__ float s[4];
    if ((tid & 63) == 0) s[tid >> 6] = acc;
    __syncthreads();
    if (tid == 0) {
        partials[(long)row * NCHUNK + chunk] = s[0] + s[1] + s[2] + s[3];
    }
}

// K2: 128 blocks x 256 threads. Block j computes t[j] directly from all
// partials: t[j] = (1/N) * sum_{m,c} Q[m,j] * partials[m,c].
// All 16K partials are L2-resident (64 KB); coalesced loads; ~2 us total
// (replaces the previous single-block latency-bound matvec).
__global__ __launch_bounds__(256) void k_matvec(const float* __restrict__ partials,
                                                const float* __restrict__ Q,
                                                float* __restrict__ t) {
    const int j   = blockIdx.x;    // 0..127
    const int tid = threadIdx.x;
    float acc = 0.f;
#pragma unroll
    for (int k = 0; k < (DOTROWS * NCHUNK) / 256; ++k) {   // 64 iters
        const int idx = tid + k * 256;
        const int m   = idx >> 7;                          // NCHUNK == 128
        acc = fmaf(partials[idx], Q[m * ROWS + j], acc);   // Q col-j loads are wave-uniform
    }
#pragma unroll
    for (int off = 32; off; off >>= 1) acc += __shfl_down(acc, off, 64);
    __shared__ float s[4];
    if ((tid & 63) == 0) s[tid >> 6] = acc;
    __syncthreads();
    if (tid == 0) t[j] = (s[0] + s[1] + s[2] + s[3]) * (1.0f / (float)NDOT);
}

// K3: row-128 update only (rows 0..127 already copied by K1).
// One column per thread: out[128,c] = Z[128,c] + sum_j t[j]*Z[j,c].
// Read-only re-read of Z -> should hit L3 (Z was just streamed by K1 and the
// copy stores were nontemporal). Writes only 1 MB.
__global__ __launch_bounds__(256) void k_row128(const float* __restrict__ Z,
                                               const float* __restrict__ t,
                                               float* __restrict__ out) {
    __shared__ float ts[DOTROWS];
    const int tid = threadIdx.x;
    if (tid < DOTROWS) ts[tid] = t[tid];
    __syncthreads();

    const long c = (long)blockIdx.x * 256 + tid;
    if (c >= NCOLS) return;

    const float* zp = Z + c;
    float acc = 0.f;
#pragma unroll 8
    for (int j = 0; j < DOTROWS; ++j) {
        acc = fmaf(ts[j], zp[(long)j * NCOLS], acc);   // conflict-free LDS broadcast
    }
    out[(long)DOTROWS * NCOLS + c] = Z[(long)DOTROWS * NCOLS + c] + acc;
}

extern "C" void kernel_launch(void* const* d_in, const int* in_sizes, int n_in,
                              void* d_out, int out_size, void* d_ws, size_t ws_size,
                              hipStream_t stream) {
    const float* Z = (const float*)d_in[0];
    // d_in[1] is P: structure (single 1 at [-1,-1]) is baked into the algorithm.
    const float* Q = (const float*)d_in[2];
    float* out = (float*)d_out;

    float* partials = (float*)d_ws;                  // DOTROWS * NCHUNK floats = 64 KB
    float* t        = partials + DOTROWS * NCHUNK;   // DOTROWS floats

    k_dot_copy<<<DOTROWS * NCHUNK, 256, 0, stream>>>(Z, out, partials);
    k_matvec<<<DOTROWS, 256, 0, stream>>>(partials, Q, t);
    k_row128<<<(NCOLS + 255) / 256, 256, 0, stream>>>(Z, t, out);
}

// Round 4
// 269.776 us; speedup vs baseline: 1.0386x; 1.0230x over previous
//
#include <hip/hip_runtime.h>

#define DD      64
#define ROWS    129        // 2D+1
#define NCOLS   262145     // N+1 (row stride, odd -> row alignment rotates with row%4)
#define NDOT    262144     // N columns participate in the dot (last col excluded)
#define DOTROWS 128        // rows 0..127 need dots (Q's last row/col are zero)
#define CHUNK   4096       // columns per block in k_dot_copy
#define NCHUNK  64         // NDOT / CHUNK

// native clang vector: required by __builtin_nontemporal_store (HIP float4 is
// a class type the builtin rejects)
typedef float f32x4 __attribute__((ext_vector_type(4)));

// Padded LDS index: element i lives at i + i/4 (stride-5 quads -> the four
// per-quad ds_read_b32 are conflict-free across lanes; unpadded 16B stride
// was an 8-way bank conflict).
#define SIDX(i) ((i) + ((i) >> 2))

// K1: grid = DOTROWS * NCHUNK blocks, 256 threads.
// Block (row, chunk): partial dot of Z[row, chunk-cols] with Z[128, chunk-cols],
// FUSED with the copy out[row, chunk-cols] = Z[row, chunk-cols].
// - dwordx4 main path; per-row alignment peel (s front scalars, 4-s tail).
// - Row-128 chunk staged to padded LDS (conflict-free scalar reads).
// - Copy stores NONTEMPORAL so Z stays L3-resident for k_row128's re-read.
__global__ __launch_bounds__(256) void k_dot_copy(const float* __restrict__ Z,
                                                  float* __restrict__ out,
                                                  float* __restrict__ partials) {
    const int row   = blockIdx.x & (DOTROWS - 1);
    const int chunk = blockIdx.x >> 7;
    const long base = (long)chunk * CHUNK;
    const long roff = (long)row * NCOLS + base;
    const float* zr = Z + roff;
    float*       orow = out + roff;
    const float* zl = Z + (long)DOTROWS * NCOLS + base;   // row 128: (128*NCOLS+base)%4==0

    const int tid = threadIdx.x;
    __shared__ float szl[CHUNK + CHUNK / 4];   // 20480 B -> 8 blocks/CU exactly

    // stage row-128 chunk into padded LDS (aligned 16B global loads)
    {
        const f32x4* zl4 = (const f32x4*)zl;
#pragma unroll
        for (int k = 0; k < CHUNK / 4 / 256; ++k) {   // 4
            const int j = tid + k * 256;
            const f32x4 v = zl4[j];
            szl[5 * j + 0] = v.x;   // SIDX(4j+r) == 5j+r
            szl[5 * j + 1] = v.y;
            szl[5 * j + 2] = v.z;
            szl[5 * j + 3] = v.w;
        }
    }
    __syncthreads();

    // alignment peel: need (row + c) % 4 == 0 for 16B-aligned vec4
    const int s  = (4 - (row & 3)) & 3;
    const int nq = (s == 0) ? CHUNK / 4 : CHUNK / 4 - 1;
    const f32x4* zr4 = (const f32x4*)(zr + s);
    f32x4*       o4  = (f32x4*)(orow + s);

    float acc = 0.f;
#pragma unroll
    for (int k = 0; k < CHUNK / 4 / 256; ++k) {   // 4
        const int q = tid + k * 256;
        if (q < nq) {
            const f32x4 v = zr4[q];
            __builtin_nontemporal_store(v, &o4[q]);
            const int c = s + 4 * q;
            acc = fmaf(v.x, szl[SIDX(c + 0)], acc);
            acc = fmaf(v.y, szl[SIDX(c + 1)], acc);
            acc = fmaf(v.z, szl[SIDX(c + 2)], acc);
            acc = fmaf(v.w, szl[SIDX(c + 3)], acc);
        }
    }
    if (s != 0) {
        if (tid < s) {                          // front scalars: cols 0..s-1
            const int c = tid;
            const float v = zr[c];
            __builtin_nontemporal_store(v, &orow[c]);
            acc = fmaf(v, szl[SIDX(c)], acc);
        } else if (tid >= 256 - (4 - s)) {      // tail scalars: cols CHUNK-4+s..CHUNK-1
            const int c = CHUNK - (256 - tid);
            const float v = zr[c];
            __builtin_nontemporal_store(v, &orow[c]);
            acc = fmaf(v, szl[SIDX(c)], acc);
        }
    }
    // tail column (col NDOT) copy, once per row: excluded from the dot
    if (chunk == NCHUNK - 1 && tid == 128) {
        __builtin_nontemporal_store(Z[(long)row * NCOLS + NDOT],
                                    &out[(long)row * NCOLS + NDOT]);
    }

    // wave reduce, then cross-wave via LDS (reuse szl after a sync)
#pragma unroll
    for (int off = 32; off; off >>= 1) acc += __shfl_down(acc, off, 64);
    __syncthreads();
    if ((tid & 63) == 0) szl[tid >> 6] = acc;
    __syncthreads();
    if (tid == 0) {
        partials[(long)row * NCHUNK + chunk] = szl[0] + szl[1] + szl[2] + szl[3];
    }
}

// K2: 128 blocks x 256 threads. Block j computes t[j] directly from all
// partials (32 KB, L2-resident): t[j] = (1/N) * sum_{m,c} Q[m,j]*partials[m,c].
__global__ __launch_bounds__(256) void k_matvec(const float* __restrict__ partials,
                                                const float* __restrict__ Q,
                                                float* __restrict__ t) {
    const int j   = blockIdx.x;    // 0..127
    const int tid = threadIdx.x;
    float acc = 0.f;
#pragma unroll
    for (int k = 0; k < (DOTROWS * NCHUNK) / 256; ++k) {   // 32
        const int idx = tid + k * 256;
        const int m   = idx >> 6;                          // NCHUNK == 64
        acc = fmaf(partials[idx], Q[m * ROWS + j], acc);   // Q load wave-uniform
    }
#pragma unroll
    for (int off = 32; off; off >>= 1) acc += __shfl_down(acc, off, 64);
    __shared__ float s[4];
    if ((tid & 63) == 0) s[tid >> 6] = acc;
    __syncthreads();
    if (tid == 0) t[j] = (s[0] + s[1] + s[2] + s[3]) * (1.0f / (float)NDOT);
}

// K3: row-128 update only (rows 0..127 already copied by K1).
// out[128,c] = Z[128,c] + sum_j t[j]*Z[j,c]. Re-read of Z should hit L3
// (K1's copy stores were nontemporal). 4 accumulators keep the strided
// loads pipelined.
__global__ __launch_bounds__(256) void k_row128(const float* __restrict__ Z,
                                               const float* __restrict__ t,
                                               float* __restrict__ out) {
    __shared__ float ts[DOTROWS];
    const int tid = threadIdx.x;
    if (tid < DOTROWS) ts[tid] = t[tid];
    __syncthreads();

    const long c = (long)blockIdx.x * 256 + tid;
    if (c >= NCOLS) return;

    const float* zp = Z + c;
    float a0 = 0.f, a1 = 0.f, a2 = 0.f, a3 = 0.f;
#pragma unroll 8
    for (int j = 0; j < DOTROWS; j += 4) {
        a0 = fmaf(ts[j + 0], zp[(long)(j + 0) * NCOLS], a0);
        a1 = fmaf(ts[j + 1], zp[(long)(j + 1) * NCOLS], a1);
        a2 = fmaf(ts[j + 2], zp[(long)(j + 2) * NCOLS], a2);
        a3 = fmaf(ts[j + 3], zp[(long)(j + 3) * NCOLS], a3);
    }
    out[(long)DOTROWS * NCOLS + c] =
        Z[(long)DOTROWS * NCOLS + c] + ((a0 + a1) + (a2 + a3));
}

extern "C" void kernel_launch(void* const* d_in, const int* in_sizes, int n_in,
                              void* d_out, int out_size, void* d_ws, size_t ws_size,
                              hipStream_t stream) {
    const float* Z = (const float*)d_in[0];
    // d_in[1] is P: structure (single 1 at [-1,-1]) is baked into the algorithm.
    const float* Q = (const float*)d_in[2];
    float* out = (float*)d_out;

    float* partials = (float*)d_ws;                  // DOTROWS * NCHUNK floats = 32 KB
    float* t        = partials + DOTROWS * NCHUNK;   // DOTROWS floats

    k_dot_copy<<<DOTROWS * NCHUNK, 256, 0, stream>>>(Z, out, partials);
    k_matvec<<<DOTROWS, 256, 0, stream>>>(partials, Q, t);
    k_row128<<<(NCOLS + 255) / 256, 256, 0, stream>>>(Z, t, out);
}